// Round 1
// baseline (30106.262 us; speedup 1.0000x reference)
//
#include <hip/hip_runtime.h>

#define BDIM 256
#define NBLK 128

typedef __bf16 bf16x8 __attribute__((ext_vector_type(8)));
typedef float  f32x4  __attribute__((ext_vector_type(4)));

__device__ __forceinline__ f32x4 mfma16(bf16x8 a, bf16x8 b, f32x4 c) {
    return __builtin_amdgcn_mfma_f32_16x16x32_bf16(a, b, c, 0, 0, 0);
}

__device__ __forceinline__ bf16x8 cvt8(const float* s) {
    f32x4 a = *(const f32x4*)s;
    f32x4 b = *(const f32x4*)(s + 4);
    bf16x8 v;
    v[0] = (__bf16)a[0]; v[1] = (__bf16)a[1]; v[2] = (__bf16)a[2]; v[3] = (__bf16)a[3];
    v[4] = (__bf16)b[0]; v[5] = (__bf16)b[1]; v[6] = (__bf16)b[2]; v[7] = (__bf16)b[3];
    return v;
}

__device__ __forceinline__ float sigm(float x) { return 1.0f / (1.0f + __expf(-x)); }
__device__ __forceinline__ float tanh_f(float x) {
    float e = __expf(2.0f * x);
    return 1.0f - 2.0f / (e + 1.0f);
}

// Grid barrier: monotonically increasing generation; counter reset by last arriver.
// All NBLK blocks are co-resident by construction (128 blocks <= 256 CUs, 1 block/CU).
__device__ __forceinline__ void gbar(int* cnt, int* gen, int target) {
    __threadfence();          // publish this thread's stores (device scope)
    __syncthreads();
    if (threadIdx.x == 0) {
        if (__hip_atomic_fetch_add(cnt, 1, __ATOMIC_ACQ_REL, __HIP_MEMORY_SCOPE_AGENT) == NBLK - 1) {
            __hip_atomic_store(cnt, 0, __ATOMIC_RELAXED, __HIP_MEMORY_SCOPE_AGENT);
            __hip_atomic_store(gen, target, __ATOMIC_RELEASE, __HIP_MEMORY_SCOPE_AGENT);
        } else {
            while (__hip_atomic_load(gen, __ATOMIC_RELAXED, __HIP_MEMORY_SCOPE_AGENT) < target) {}
            (void)__hip_atomic_load(gen, __ATOMIC_ACQUIRE, __HIP_MEMORY_SCOPE_AGENT);
        }
    }
    __syncthreads();
}

__global__ __launch_bounds__(BDIM, 1)
void lstm_ode_persist(const float* __restrict__ xin,     // [128][1024][128]
                      const float* __restrict__ Wih,     // [2048][128]
                      const float* __restrict__ Whh,     // [2048][512]
                      const float* __restrict__ bih,     // [2048]
                      const float* __restrict__ bhh,     // [2048]
                      const float* __restrict__ ow1,     // [1024][512]
                      const float* __restrict__ ob1,     // [1024]
                      const float* __restrict__ ow2,     // [1024][1024]
                      const float* __restrict__ ob2,     // [1024]
                      const float* __restrict__ ow3,     // [512][1024]
                      const float* __restrict__ ob3,     // [512]
                      const float* __restrict__ dw1,     // [1024][512]
                      const float* __restrict__ db1,     // [1024]
                      const float* __restrict__ dw2,     // [128][1024]
                      const float* __restrict__ db2,     // [128]
                      float* __restrict__ outp,          // [128][5][128]
                      int* cnt, int* gen,
                      __bf16* __restrict__ hbuf,         // [2][128][512]
                      __bf16* __restrict__ zin,          // [128][512]
                      __bf16* __restrict__ u1,           // [128][1024]
                      __bf16* __restrict__ u2,           // [128][1024]
                      __bf16* __restrict__ predz,        // [640][512]  (row = b*5+s)
                      __bf16* __restrict__ decu,         // [640][1024]
                      __bf16* __restrict__ dw1b,         // [1024][512]
                      __bf16* __restrict__ dw2b)         // [128][1024]
{
    const int tid = threadIdx.x;
    const int bid = blockIdx.x;
    const int wv  = tid >> 6;         // wave 0..3
    const int ln  = tid & 63;
    const int l15 = ln & 15;
    const int lq  = ln >> 4;          // 0..3
    const int mg  = bid & 1;          // M-group (64 rows)
    const int jg  = bid >> 1;         // 0..63 (j-group)
    int barc = 0;

    const int browA = mg * 64 + wv * 16 + l15;      // A-frag row (b)
    const int browC = mg * 64 + wv * 16 + lq * 4;   // C/D row base (+r)

    __shared__ __bf16 w2s[16 * 1032];               // ODE w2 slice [16][1032]

    // ---------------- init: convert decoder weights, zero h buffer 0 ------------
    const int gtid = bid * BDIM + tid;
    for (int i = gtid; i < 1024 * 512; i += NBLK * BDIM) dw1b[i] = (__bf16)dw1[i];
    for (int i = gtid; i < 128 * 1024; i += NBLK * BDIM) dw2b[i] = (__bf16)dw2[i];
    for (int i = gtid; i < 128 * 512;  i += NBLK * BDIM) hbuf[i] = (__bf16)0.0f;

    // ---------------- LSTM weight fragments in registers -----------------------
    // block owns gate cols {g*512 + jg*8 + jj : g in 0..3, jj in 0..7} -> local n = g*8+jj
    bf16x8 breg[2][20];
#pragma unroll
    for (int s = 0; s < 2; ++s) {
        const int ncol = s * 16 + l15;
        const int gate = ncol >> 3;
        const int jj   = ncol & 7;
        const int wrow = gate * 512 + jg * 8 + jj;
#pragma unroll
        for (int kc = 0; kc < 20; ++kc) {
            const float* src = (kc < 4) ? (Wih + (size_t)wrow * 128 + kc * 32 + lq * 8)
                                        : (Whh + (size_t)wrow * 512 + (kc - 4) * 32 + lq * 8);
            breg[s][kc] = cvt8(src);
        }
    }
    float bias0, bias1;
    {
        int nc = l15;      int g = nc >> 3, jj = nc & 7; int r0 = g * 512 + jg * 8 + jj;
        bias0 = bih[r0] + bhh[r0];
        nc = 16 + l15;     g = nc >> 3; jj = nc & 7;     int r1 = g * 512 + jg * 8 + jj;
        bias1 = bih[r1] + bhh[r1];
    }
    float c_reg[4] = {0.f, 0.f, 0.f, 0.f};

    gbar(cnt, gen, ++barc);   // hbuf[0] zeroed, dec weights converted

    // ---------------- LSTM loop -------------------------------------------------
    for (int t = 0; t < 1024; ++t) {
        const int rp = t & 1, wp = rp ^ 1;
        f32x4 acc[2][2] = {};
        // x part (K cols 0..127)
#pragma unroll
        for (int kc = 0; kc < 4; ++kc) {
            const float* xs = xin + ((size_t)browA * 1024 + t) * 128 + kc * 32 + lq * 8;
            bf16x8 av = cvt8(xs);
            acc[0][kc & 1] = mfma16(av, breg[0][kc], acc[0][kc & 1]);
            acc[1][kc & 1] = mfma16(av, breg[1][kc], acc[1][kc & 1]);
        }
        // h part (K cols 128..639)
        const __bf16* hb = hbuf + (size_t)rp * 128 * 512;
#pragma unroll
        for (int kc = 4; kc < 20; ++kc) {
            bf16x8 av = *(const bf16x8*)(hb + (size_t)browA * 512 + (kc - 4) * 32 + lq * 8);
            acc[0][kc & 1] = mfma16(av, breg[0][kc], acc[0][kc & 1]);
            acc[1][kc & 1] = mfma16(av, breg[1][kc], acc[1][kc & 1]);
        }
        // epilogue: gates -> c,h   (i at n=0..7, f at 8..15, g at 16..23, o at 24..31)
        __bf16* hw = hbuf + (size_t)wp * 128 * 512;
#pragma unroll
        for (int r = 0; r < 4; ++r) {
            float v0 = acc[0][0][r] + acc[0][1][r] + bias0;
            float v1 = acc[1][0][r] + acc[1][1][r] + bias1;
            float p0 = __shfl_xor(v0, 8, 64);
            float p1 = __shfl_xor(v1, 8, 64);
            if (l15 < 8) {
                float ig = sigm(v0), fg = sigm(p0);
                float gg = tanh_f(v1), og = sigm(p1);
                float cn = fg * c_reg[r] + ig * gg;
                c_reg[r] = cn;
                float hn = og * tanh_f(cn);
                hw[(size_t)(browC + r) * 512 + jg * 8 + l15] = (__bf16)hn;
            }
        }
        gbar(cnt, gen, ++barc);
    }

    // ---------------- ODE setup -------------------------------------------------
    // z0 = c_n ; same (b,j) lane ownership as LSTM -> z stays in registers.
#pragma unroll
    for (int r = 0; r < 4; ++r) {
        if (l15 < 8) {
            const int b = browC + r, j = jg * 8 + l15;
            zin[(size_t)b * 512 + j] = (__bf16)c_reg[r];
            predz[((size_t)b * 5 + 0) * 512 + j] = (__bf16)c_reg[r];
        }
    }
    // stage w2 slice (rows jg*16..+15) into LDS
    for (int i = tid; i < 16 * 1024; i += BDIM) {
        int rr = i >> 10, kk = i & 1023;
        w2s[rr * 1032 + kk] = (__bf16)ow2[(size_t)(jg * 16 + rr) * 1024 + kk];
    }
    __syncthreads();
    bf16x8 w1reg[16];
#pragma unroll
    for (int kc = 0; kc < 16; ++kc)
        w1reg[kc] = cvt8(ow1 + (size_t)(jg * 16 + l15) * 512 + kc * 32 + lq * 8);
    bf16x8 w3reg[32];
#pragma unroll
    for (int kc = 0; kc < 32; ++kc) {
        bf16x8 v;
#pragma unroll
        for (int q = 0; q < 8; ++q) v[q] = (__bf16)0.0f;
        if (l15 < 8) v = cvt8(ow3 + (size_t)(jg * 8 + l15) * 1024 + kc * 32 + lq * 8);
        w3reg[kc] = v;
    }
    const float b1c = ob1[jg * 16 + l15];
    const float b2c = ob2[jg * 16 + l15];
    const float b3c = (l15 < 8) ? ob3[jg * 8 + l15] : 0.0f;
    float z_reg[4], kacc[4];
#pragma unroll
    for (int r = 0; r < 4; ++r) { z_reg[r] = c_reg[r]; kacc[r] = 0.f; }

    gbar(cnt, gen, ++barc);   // zin visible

    const float dt = 5.0f / 480.0f;   // (5/60)/8
    // ---------------- ODE loop: 4 intervals x 8 substeps x RK4 ------------------
    for (int it = 0; it < 4; ++it) {
        for (int sub = 0; sub < 8; ++sub) {
            for (int st = 0; st < 4; ++st) {
                // G1: u1 = elu(zin @ w1^T + b1)   [K=512]
                {
                    f32x4 a4[4] = {};
#pragma unroll
                    for (int kc = 0; kc < 16; ++kc) {
                        bf16x8 av = *(const bf16x8*)(zin + (size_t)browA * 512 + kc * 32 + lq * 8);
                        a4[kc & 3] = mfma16(av, w1reg[kc], a4[kc & 3]);
                    }
#pragma unroll
                    for (int r = 0; r < 4; ++r) {
                        float v = a4[0][r] + a4[1][r] + a4[2][r] + a4[3][r] + b1c;
                        v = v > 0.f ? v : __expf(v) - 1.0f;
                        u1[(size_t)(browC + r) * 1024 + jg * 16 + l15] = (__bf16)v;
                    }
                }
                gbar(cnt, gen, ++barc);
                // G2: u2 = elu(u1 @ w2^T + b2)    [K=1024]
                {
                    f32x4 a4[4] = {};
#pragma unroll
                    for (int kc = 0; kc < 32; ++kc) {
                        bf16x8 av = *(const bf16x8*)(u1 + (size_t)browA * 1024 + kc * 32 + lq * 8);
                        bf16x8 bv = *(const bf16x8*)(&w2s[l15 * 1032 + kc * 32 + lq * 8]);
                        a4[kc & 3] = mfma16(av, bv, a4[kc & 3]);
                    }
#pragma unroll
                    for (int r = 0; r < 4; ++r) {
                        float v = a4[0][r] + a4[1][r] + a4[2][r] + a4[3][r] + b2c;
                        v = v > 0.f ? v : __expf(v) - 1.0f;
                        u2[(size_t)(browC + r) * 1024 + jg * 16 + l15] = (__bf16)v;
                    }
                }
                gbar(cnt, gen, ++barc);
                // G3: k = u2 @ w3^T + b3 ; RK4 bookkeeping   [K=1024]
                {
                    f32x4 a4[4] = {};
#pragma unroll
                    for (int kc = 0; kc < 32; ++kc) {
                        bf16x8 av = *(const bf16x8*)(u2 + (size_t)browA * 1024 + kc * 32 + lq * 8);
                        a4[kc & 3] = mfma16(av, w3reg[kc], a4[kc & 3]);
                    }
                    if (l15 < 8) {
#pragma unroll
                        for (int r = 0; r < 4; ++r) {
                            float kv = a4[0][r] + a4[1][r] + a4[2][r] + a4[3][r] + b3c;
                            float zt;
                            if (st == 0)      { kacc[r] = kv;          zt = z_reg[r] + 0.5f * dt * kv; }
                            else if (st == 1) { kacc[r] += 2.f * kv;   zt = z_reg[r] + 0.5f * dt * kv; }
                            else if (st == 2) { kacc[r] += 2.f * kv;   zt = z_reg[r] + dt * kv; }
                            else              { z_reg[r] += (dt / 6.f) * (kacc[r] + kv); zt = z_reg[r]; }
                            const int b = browC + r, j = jg * 8 + l15;
                            zin[(size_t)b * 512 + j] = (__bf16)zt;
                            if (st == 3 && sub == 7)
                                predz[((size_t)b * 5 + it + 1) * 512 + j] = (__bf16)zt;
                        }
                    }
                }
                gbar(cnt, gen, ++barc);
            }
        }
    }

    // ---------------- decoder ---------------------------------------------------
    // D1: decu = relu(predz @ dw1^T + db1)  : tiles 40(M) x 64(N), K=512
    const int gid = bid * 4 + wv;
    for (int tt = gid; tt < 2560; tt += NBLK * 4) {
        const int m = tt >> 6, n = tt & 63;
        f32x4 a4[4] = {};
#pragma unroll
        for (int kc = 0; kc < 16; ++kc) {
            bf16x8 av = *(const bf16x8*)(predz + (size_t)(m * 16 + l15) * 512 + kc * 32 + lq * 8);
            bf16x8 bv = *(const bf16x8*)(dw1b + (size_t)(n * 16 + l15) * 512 + kc * 32 + lq * 8);
            a4[kc & 3] = mfma16(av, bv, a4[kc & 3]);
        }
        const float bb = db1[n * 16 + l15];
#pragma unroll
        for (int r = 0; r < 4; ++r) {
            float v = a4[0][r] + a4[1][r] + a4[2][r] + a4[3][r] + bb;
            v = fmaxf(v, 0.0f);
            decu[(size_t)(m * 16 + lq * 4 + r) * 1024 + n * 16 + l15] = (__bf16)v;
        }
    }
    gbar(cnt, gen, ++barc);
    // D2: out = decu @ dw2^T + db2 : tiles 40(M) x 8(N), K=1024
    if (gid < 320) {
        const int m = gid >> 3, n = gid & 7;
        f32x4 a4[4] = {};
#pragma unroll
        for (int kc = 0; kc < 32; ++kc) {
            bf16x8 av = *(const bf16x8*)(decu + (size_t)(m * 16 + l15) * 1024 + kc * 32 + lq * 8);
            bf16x8 bv = *(const bf16x8*)(dw2b + (size_t)(n * 16 + l15) * 1024 + kc * 32 + lq * 8);
            a4[kc & 3] = mfma16(av, bv, a4[kc & 3]);
        }
        const float bb = db2[n * 16 + l15];
#pragma unroll
        for (int r = 0; r < 4; ++r) {
            outp[(size_t)(m * 16 + lq * 4 + r) * 128 + n * 16 + l15] =
                a4[0][r] + a4[1][r] + a4[2][r] + a4[3][r] + bb;
        }
    }
}

extern "C" void kernel_launch(void* const* d_in, const int* in_sizes, int n_in,
                              void* d_out, int out_size, void* d_ws, size_t ws_size,
                              hipStream_t stream) {
    (void)in_sizes; (void)n_in; (void)out_size;
    const float* xin = (const float*)d_in[0];
    // d_in[1] targets, d_in[2] target_len : unused
    const float* Wih = (const float*)d_in[3];
    const float* Whh = (const float*)d_in[4];
    const float* bih = (const float*)d_in[5];
    const float* bhh = (const float*)d_in[6];
    const float* ow1 = (const float*)d_in[7];
    const float* ob1 = (const float*)d_in[8];
    const float* ow2 = (const float*)d_in[9];
    const float* ob2 = (const float*)d_in[10];
    const float* ow3 = (const float*)d_in[11];
    const float* ob3 = (const float*)d_in[12];
    const float* dw1 = (const float*)d_in[13];
    const float* db1 = (const float*)d_in[14];
    const float* dw2 = (const float*)d_in[15];
    const float* db2 = (const float*)d_in[16];
    float* outp = (float*)d_out;

    char* ws = (char*)d_ws;
    // barrier state in first 4KB (zeroed every call)
    hipMemsetAsync(ws, 0, 4096, stream);
    int* cnt = (int*)ws;
    int* gen = (int*)(ws + 128);
    size_t off = 4096;
    __bf16* hbuf  = (__bf16*)(ws + off); off += (size_t)2 * 128 * 512 * 2;
    __bf16* zin   = (__bf16*)(ws + off); off += (size_t)128 * 512 * 2;
    __bf16* u1    = (__bf16*)(ws + off); off += (size_t)128 * 1024 * 2;
    __bf16* u2    = (__bf16*)(ws + off); off += (size_t)128 * 1024 * 2;
    __bf16* predz = (__bf16*)(ws + off); off += (size_t)640 * 512 * 2;
    __bf16* decu  = (__bf16*)(ws + off); off += (size_t)640 * 1024 * 2;
    __bf16* dw1b  = (__bf16*)(ws + off); off += (size_t)1024 * 512 * 2;
    __bf16* dw2b  = (__bf16*)(ws + off); off += (size_t)128 * 1024 * 2;
    (void)ws_size;

    hipLaunchKernelGGL(lstm_ode_persist, dim3(NBLK), dim3(BDIM), 0, stream,
                       xin, Wih, Whh, bih, bhh, ow1, ob1, ow2, ob2, ow3, ob3,
                       dw1, db1, dw2, db2, outp, cnt, gen,
                       hbuf, zin, u1, u2, predz, decu, dw1b, dw2b);
}

// Round 2
// 10401.231 us; speedup vs baseline: 2.8945x; 2.8945x over previous
//
#include <hip/hip_runtime.h>

#define BDIM 256
#define NBLK 128
#define GSZ  16    // blocks per group (must be power of 2)
#define NG   8     // groups

typedef __bf16 bf16x8 __attribute__((ext_vector_type(8)));
typedef float  f32x4  __attribute__((ext_vector_type(4)));

__device__ __forceinline__ f32x4 mfma16(bf16x8 a, bf16x8 b, f32x4 c) {
    return __builtin_amdgcn_mfma_f32_16x16x32_bf16(a, b, c, 0, 0, 0);
}

__device__ __forceinline__ bf16x8 cvt8(const float* s) {
    f32x4 a = *(const f32x4*)s;
    f32x4 b = *(const f32x4*)(s + 4);
    bf16x8 v;
    v[0] = (__bf16)a[0]; v[1] = (__bf16)a[1]; v[2] = (__bf16)a[2]; v[3] = (__bf16)a[3];
    v[4] = (__bf16)b[0]; v[5] = (__bf16)b[1]; v[6] = (__bf16)b[2]; v[7] = (__bf16)b[3];
    return v;
}

// L3-coherent (agent-scope) 16B load as two 8B relaxed atomic loads.
__device__ __forceinline__ bf16x8 ld8_sc(const __bf16* p) {
    union { bf16x8 v; unsigned long long u[2]; } r;
    const unsigned long long* q = (const unsigned long long*)p;
    r.u[0] = __hip_atomic_load(q,     __ATOMIC_RELAXED, __HIP_MEMORY_SCOPE_AGENT);
    r.u[1] = __hip_atomic_load(q + 1, __ATOMIC_RELAXED, __HIP_MEMORY_SCOPE_AGENT);
    return r.v;
}

// L3-coherent 2B store of a float converted to bf16.
__device__ __forceinline__ void st2_sc(__bf16* p, float v) {
    __bf16 b = (__bf16)v;
    unsigned short u;
    __builtin_memcpy(&u, &b, 2);
    __hip_atomic_store((unsigned short*)p, u, __ATOMIC_RELAXED, __HIP_MEMORY_SCOPE_AGENT);
}

__device__ __forceinline__ float sigm(float x) { return 1.0f / (1.0f + __expf(-x)); }
__device__ __forceinline__ float tanh_f(float x) {
    float e = __expf(2.0f * x);
    return 1.0f - 2.0f / (e + 1.0f);
}

// Monotonic-counter barrier, no reset (last arriver of round k sees old == k*nmem-1).
// No fences: all communicated data travels via sc1 (agent-scope) accesses, so no
// L2 writeback/invalidate is needed; vmcnt(0) + syncthreads orders the stores.
__device__ __forceinline__ void g_arrive(int* cnt, int* gen, int target, int nmem) {
    asm volatile("s_waitcnt vmcnt(0)" ::: "memory");
    __syncthreads();
    if (threadIdx.x == 0) {
        int old = __hip_atomic_fetch_add(cnt, 1, __ATOMIC_RELAXED, __HIP_MEMORY_SCOPE_AGENT);
        if (((old + 1) & (nmem - 1)) == 0)
            __hip_atomic_store(gen, (old + 1) / nmem, __ATOMIC_RELAXED, __HIP_MEMORY_SCOPE_AGENT);
    }
    (void)target;
}

__device__ __forceinline__ void g_wait(int* gen, int target) {
    if (threadIdx.x == 0) {
        while (__hip_atomic_load(gen, __ATOMIC_RELAXED, __HIP_MEMORY_SCOPE_AGENT) < target) {}
    }
    __syncthreads();
    __builtin_amdgcn_sched_barrier(0);
}

__global__ __launch_bounds__(BDIM, 1)
void lstm_ode_persist(const float* __restrict__ xin,     // [128][1024][128]
                      const float* __restrict__ Wih,     // [2048][128]
                      const float* __restrict__ Whh,     // [2048][512]
                      const float* __restrict__ bih,     // [2048]
                      const float* __restrict__ bhh,     // [2048]
                      const float* __restrict__ ow1,     // [1024][512]
                      const float* __restrict__ ob1,     // [1024]
                      const float* __restrict__ ow2,     // [1024][1024]
                      const float* __restrict__ ob2,     // [1024]
                      const float* __restrict__ ow3,     // [512][1024]
                      const float* __restrict__ ob3,     // [512]
                      const float* __restrict__ dw1,     // [1024][512]
                      const float* __restrict__ db1,     // [1024]
                      const float* __restrict__ dw2,     // [128][1024]
                      const float* __restrict__ db2,     // [128]
                      float* __restrict__ outp,          // [128][5][128]
                      int* __restrict__ bar,             // barrier lines
                      __bf16* __restrict__ hbuf,         // [2][128][512]
                      __bf16* __restrict__ zin,          // [128][512]
                      __bf16* __restrict__ u1,           // [128][1024]
                      __bf16* __restrict__ u2,           // [128][1024]
                      __bf16* __restrict__ predz,        // [640][512] (row = b*5+s)
                      __bf16* __restrict__ decu)         // [640][1024]
{
    extern __shared__ __bf16 w2s[];                      // [64][1032] ODE w2 slice

    const int tid = threadIdx.x;
    const int bid = blockIdx.x;
    const int wv  = tid >> 6;          // wave 0..3
    const int ln  = tid & 63;
    const int l15 = ln & 15;
    const int lq  = ln >> 4;           // 0..3
    const int g   = bid >> 4;          // group 0..7 (16 batch rows each)
    const int m   = bid & 15;          // member 0..15 (column slice)
    const int R0  = g * 16;            // batch rows R0..R0+15
    const int J0  = m * 32;            // LSTM hidden cols J0..J0+31
    const int U0  = m * 64;            // ODE u-cols  U0..U0+63
    const int Z0  = m * 32;            // ODE z-cols  Z0..Z0+31

    int* gcnt = bar + (g * 256) / 4;
    int* ggen = bar + (g * 256 + 128) / 4;
    int* ccnt = bar + 2048 / 4;
    int* cgen = bar + (2048 + 128) / 4;
    int barc = 0;

    // ---------------- LSTM weights -> registers --------------------------------
    // wave wv owns j-cols J0+wv*8..+7, all 4 gates (i,f,g,o) as 2 N-tiles of 16.
    bf16x8 breg[2][20];
    float bias[2];
#pragma unroll
    for (int s = 0; s < 2; ++s) {
        const int ncol = s * 16 + l15;
        const int gate = ncol >> 3;
        const int jj   = ncol & 7;
        const int wrow = gate * 512 + J0 + wv * 8 + jj;
#pragma unroll
        for (int kc = 0; kc < 20; ++kc) {
            const float* src = (kc < 4) ? (Wih + (size_t)wrow * 128 + kc * 32 + lq * 8)
                                        : (Whh + (size_t)wrow * 512 + (kc - 4) * 32 + lq * 8);
            breg[s][kc] = cvt8(src);
        }
        bias[s] = bih[wrow] + bhh[wrow];
    }
    float c_reg[4] = {0.f, 0.f, 0.f, 0.f};

    // ---------------- LSTM loop ------------------------------------------------
    for (int t = 0; t < 1024; ++t) {
        f32x4 acc[2][2] = {};
        // x part (independent of h: overlaps the group barrier wait)
#pragma unroll
        for (int kc = 0; kc < 4; ++kc) {
            const float* xs = xin + ((size_t)(R0 + l15) * 1024 + t) * 128 + kc * 32 + lq * 8;
            bf16x8 av = cvt8(xs);
            acc[0][kc & 1] = mfma16(av, breg[0][kc], acc[0][kc & 1]);
            acc[1][kc & 1] = mfma16(av, breg[1][kc], acc[1][kc & 1]);
        }
        if (t > 0) {
            g_wait(ggen, barc);                    // h_{t-1} visible (gen == t)
            const __bf16* hb = hbuf + (size_t)((t + 1) & 1) * 128 * 512;
#pragma unroll
            for (int kc = 4; kc < 20; ++kc) {
                bf16x8 av = ld8_sc(hb + (size_t)(R0 + l15) * 512 + (kc - 4) * 32 + lq * 8);
                acc[0][kc & 1] = mfma16(av, breg[0][kc], acc[0][kc & 1]);
                acc[1][kc & 1] = mfma16(av, breg[1][kc], acc[1][kc & 1]);
            }
        }
        __bf16* hw = hbuf + (size_t)(t & 1) * 128 * 512;
#pragma unroll
        for (int r = 0; r < 4; ++r) {
            float v0 = acc[0][0][r] + acc[0][1][r] + bias[0];
            float v1 = acc[1][0][r] + acc[1][1][r] + bias[1];
            float p0 = __shfl_xor(v0, 8, 64);
            float p1 = __shfl_xor(v1, 8, 64);
            if (l15 < 8) {
                float ig = sigm(v0), fg = sigm(p0);
                float gg = tanh_f(v1), og = sigm(p1);
                float cn = fg * c_reg[r] + ig * gg;
                c_reg[r] = cn;
                if (t < 1023) {
                    float hn = og * tanh_f(cn);
                    st2_sc(hw + (size_t)(R0 + lq * 4 + r) * 512 + J0 + wv * 8 + l15, hn);
                }
            }
        }
        if (t < 1023) { ++barc; g_arrive(gcnt, ggen, barc, GSZ); }
    }

    // ---------------- z0 = c_n ; stage ODE weights -----------------------------
#pragma unroll
    for (int r = 0; r < 4; ++r) {
        if (l15 < 8) {
            const int b = R0 + lq * 4 + r, j = J0 + wv * 8 + l15;
            st2_sc(zin + (size_t)b * 512 + j, c_reg[r]);
            st2_sc(predz + ((size_t)b * 5 + 0) * 512 + j, c_reg[r]);
        }
    }
    ++barc; g_arrive(gcnt, ggen, barc, GSZ);
    // stage w2 slice [64][1032] into LDS while waiting (plain reads: ow2 is read-only)
    for (int i = tid; i < 64 * 1024; i += BDIM) {
        int rr = i >> 10, kk = i & 1023;
        w2s[rr * 1032 + kk] = (__bf16)ow2[(size_t)(U0 + rr) * 1024 + kk];
    }
    bf16x8 w1reg[16];
#pragma unroll
    for (int kc = 0; kc < 16; ++kc)
        w1reg[kc] = cvt8(ow1 + (size_t)(U0 + wv * 16 + l15) * 512 + kc * 32 + lq * 8);
    bf16x8 w3reg[32];
#pragma unroll
    for (int kc = 0; kc < 32; ++kc) {
        bf16x8 v;
#pragma unroll
        for (int q = 0; q < 8; ++q) v[q] = (__bf16)0.0f;
        if (l15 < 8) v = cvt8(ow3 + (size_t)(Z0 + wv * 8 + l15) * 1024 + kc * 32 + lq * 8);
        w3reg[kc] = v;
    }
    const float b1c = ob1[U0 + wv * 16 + l15];
    const float b2c = ob2[U0 + wv * 16 + l15];
    const float b3c = (l15 < 8) ? ob3[Z0 + wv * 8 + l15] : 0.0f;
    float z_reg[4], kacc[4];
#pragma unroll
    for (int r = 0; r < 4; ++r) { z_reg[r] = c_reg[r]; kacc[r] = 0.f; }
    g_wait(ggen, barc);   // zin visible; also fences the LDS staging via syncthreads

    const float dt = 5.0f / 480.0f;   // (5/60)/8
    // ---------------- ODE: 4 intervals x 8 substeps x 4 RK stages --------------
    for (int it = 0; it < 4; ++it) {
        for (int sub = 0; sub < 8; ++sub) {
            for (int st = 0; st < 4; ++st) {
                // G1: u1 = elu(z @ w1^T + b1), K=512, block cols U0..U0+63
                {
                    f32x4 a4[2] = {};
#pragma unroll
                    for (int kc = 0; kc < 16; ++kc) {
                        bf16x8 av = ld8_sc(zin + (size_t)(R0 + l15) * 512 + kc * 32 + lq * 8);
                        a4[kc & 1] = mfma16(av, w1reg[kc], a4[kc & 1]);
                    }
#pragma unroll
                    for (int r = 0; r < 4; ++r) {
                        float v = a4[0][r] + a4[1][r] + b1c;
                        v = v > 0.f ? v : __expf(v) - 1.0f;
                        st2_sc(u1 + (size_t)(R0 + lq * 4 + r) * 1024 + U0 + wv * 16 + l15, v);
                    }
                }
                ++barc; g_arrive(gcnt, ggen, barc, GSZ); g_wait(ggen, barc);
                // G2: u2 = elu(u1 @ w2^T + b2), K=1024, weights from LDS
                {
                    f32x4 a4[2] = {};
#pragma unroll
                    for (int kc = 0; kc < 32; ++kc) {
                        bf16x8 av = ld8_sc(u1 + (size_t)(R0 + l15) * 1024 + kc * 32 + lq * 8);
                        bf16x8 bv = *(const bf16x8*)&w2s[(wv * 16 + l15) * 1032 + kc * 32 + lq * 8];
                        a4[kc & 1] = mfma16(av, bv, a4[kc & 1]);
                    }
#pragma unroll
                    for (int r = 0; r < 4; ++r) {
                        float v = a4[0][r] + a4[1][r] + b2c;
                        v = v > 0.f ? v : __expf(v) - 1.0f;
                        st2_sc(u2 + (size_t)(R0 + lq * 4 + r) * 1024 + U0 + wv * 16 + l15, v);
                    }
                }
                ++barc; g_arrive(gcnt, ggen, barc, GSZ); g_wait(ggen, barc);
                // G3: k = u2 @ w3^T + b3 ; RK4 bookkeeping; block cols Z0..Z0+31
                {
                    f32x4 a4[2] = {};
#pragma unroll
                    for (int kc = 0; kc < 32; ++kc) {
                        bf16x8 av = ld8_sc(u2 + (size_t)(R0 + l15) * 1024 + kc * 32 + lq * 8);
                        a4[kc & 1] = mfma16(av, w3reg[kc], a4[kc & 1]);
                    }
                    if (l15 < 8) {
#pragma unroll
                        for (int r = 0; r < 4; ++r) {
                            float kv = a4[0][r] + a4[1][r] + b3c;
                            float zt;
                            if (st == 0)      { kacc[r] = kv;         zt = z_reg[r] + 0.5f * dt * kv; }
                            else if (st == 1) { kacc[r] += 2.f * kv;  zt = z_reg[r] + 0.5f * dt * kv; }
                            else if (st == 2) { kacc[r] += 2.f * kv;  zt = z_reg[r] + dt * kv; }
                            else              { z_reg[r] += (dt / 6.f) * (kacc[r] + kv); zt = z_reg[r]; }
                            const int b = R0 + lq * 4 + r, j = Z0 + wv * 8 + l15;
                            st2_sc(zin + (size_t)b * 512 + j, zt);
                            if (st == 3 && sub == 7)
                                st2_sc(predz + ((size_t)b * 5 + it + 1) * 512 + j, zt);
                        }
                    }
                }
                ++barc; g_arrive(gcnt, ggen, barc, GSZ); g_wait(ggen, barc);
            }
        }
    }

    // ---------------- full-grid barrier, then decoder --------------------------
    g_arrive(ccnt, cgen, 1, NBLK); g_wait(cgen, 1);

    // D1: decu = relu(predz @ dw1^T + db1) : 40(M) x 64(N) tiles, K=512
    const int gid = bid * 4 + wv;
    for (int tt = gid; tt < 2560; tt += NBLK * 4) {
        const int mt = tt >> 6, nt = tt & 63;
        f32x4 a4[2] = {};
#pragma unroll
        for (int kc = 0; kc < 16; ++kc) {
            bf16x8 av = ld8_sc(predz + (size_t)(mt * 16 + l15) * 512 + kc * 32 + lq * 8);
            bf16x8 bv = cvt8(dw1 + (size_t)(nt * 16 + l15) * 512 + kc * 32 + lq * 8);
            a4[kc & 1] = mfma16(av, bv, a4[kc & 1]);
        }
        const float bb = db1[nt * 16 + l15];
#pragma unroll
        for (int r = 0; r < 4; ++r) {
            float v = fmaxf(a4[0][r] + a4[1][r] + bb, 0.0f);
            st2_sc(decu + (size_t)(mt * 16 + lq * 4 + r) * 1024 + nt * 16 + l15, v);
        }
    }
    g_arrive(ccnt, cgen, 2, NBLK); g_wait(cgen, 2);

    // D2: out = decu @ dw2^T + db2 : 40(M) x 8(N) tiles, K=1024
    if (gid < 320) {
        const int mt = gid >> 3, nt = gid & 7;
        f32x4 a4[2] = {};
#pragma unroll
        for (int kc = 0; kc < 32; ++kc) {
            bf16x8 av = ld8_sc(decu + (size_t)(mt * 16 + l15) * 1024 + kc * 32 + lq * 8);
            bf16x8 bv = cvt8(dw2 + (size_t)(nt * 16 + l15) * 1024 + kc * 32 + lq * 8);
            a4[kc & 1] = mfma16(av, bv, a4[kc & 1]);
        }
        const float bb = db2[nt * 16 + l15];
#pragma unroll
        for (int r = 0; r < 4; ++r) {
            outp[(size_t)(mt * 16 + lq * 4 + r) * 128 + nt * 16 + l15] =
                a4[0][r] + a4[1][r] + bb;
        }
    }
}

extern "C" void kernel_launch(void* const* d_in, const int* in_sizes, int n_in,
                              void* d_out, int out_size, void* d_ws, size_t ws_size,
                              hipStream_t stream) {
    (void)in_sizes; (void)n_in; (void)out_size; (void)ws_size;
    const float* xin = (const float*)d_in[0];
    const float* Wih = (const float*)d_in[3];
    const float* Whh = (const float*)d_in[4];
    const float* bih = (const float*)d_in[5];
    const float* bhh = (const float*)d_in[6];
    const float* ow1 = (const float*)d_in[7];
    const float* ob1 = (const float*)d_in[8];
    const float* ow2 = (const float*)d_in[9];
    const float* ob2 = (const float*)d_in[10];
    const float* ow3 = (const float*)d_in[11];
    const float* ob3 = (const float*)d_in[12];
    const float* dw1 = (const float*)d_in[13];
    const float* db1 = (const float*)d_in[14];
    const float* dw2 = (const float*)d_in[15];
    const float* db2 = (const float*)d_in[16];
    float* outp = (float*)d_out;

    char* ws = (char*)d_ws;
    hipMemsetAsync(ws, 0, 4096, stream);          // barrier lines
    int* bar = (int*)ws;
    size_t off = 4096;
    __bf16* hbuf  = (__bf16*)(ws + off); off += (size_t)2 * 128 * 512 * 2;
    __bf16* zin   = (__bf16*)(ws + off); off += (size_t)128 * 512 * 2;
    __bf16* u1b   = (__bf16*)(ws + off); off += (size_t)128 * 1024 * 2;
    __bf16* u2b   = (__bf16*)(ws + off); off += (size_t)128 * 1024 * 2;
    __bf16* predz = (__bf16*)(ws + off); off += (size_t)640 * 512 * 2;
    __bf16* decu  = (__bf16*)(ws + off); off += (size_t)640 * 1024 * 2;

    const size_t shmem = (size_t)64 * 1032 * 2;   // 132096 B dynamic LDS
    hipFuncSetAttribute((const void*)lstm_ode_persist,
                        hipFuncAttributeMaxDynamicSharedMemorySize, (int)shmem);

    hipLaunchKernelGGL(lstm_ode_persist, dim3(NBLK), dim3(BDIM), shmem, stream,
                       xin, Wih, Whh, bih, bhh, ow1, ob1, ow2, ob2, ow3, ob3,
                       dw1, db1, dw2, db2, outp, bar,
                       hbuf, zin, u1b, u2b, predz, decu);
}